// Round 15
// baseline (483.910 us; speedup 1.0000x reference)
//
#include <hip/hip_runtime.h>
#include <stdint.h>

// Problem constants (B,T,C,DD) = (32, 2048, 32, 8)
#define BB 32
#define TT 2048
#define CC 32
#define DDIM 8
#define FF 42                  // DEPTH + 2 = (8+32) + 2
#define NCH (CC + DDIM)        // 40 output channels
#define SLAB_B (TT * FF)       // 86016 elems per (ch,b)
#define SLAB_CH (BB * SLAB_B)  // 2752512 elems per ch
#define TOTAL (40L * SLAB_CH)  // 110100480 elems (f32!)

// Mask element layout from OR of first 256 words (1 KB):
//   mode 0: 4-byte 0/1 (int32, or f32 0.0/1.0)  -> read word
//   mode 1: 1-byte bool                          -> read byte
//   mode 2: 2-byte 0/1                           -> read short
//   mode 3: 8-byte 0/1 (int64, LE: odd words 0)  -> read qword
__device__ __forceinline__ int detect_mask_mode(const void* meas) {
    const unsigned* w = (const unsigned*)meas;
    unsigned A = 0, Aodd = 0;
    for (int i = 0; i < 256; ++i) A |= w[i];
    for (int i = 1; i < 256; i += 2) Aodd |= w[i];
    unsigned hi = A >> 24;
    if (hi == 0u) return (Aodd == 0u) ? 3 : 0;
    if (hi >= 0x3Cu && hi <= 0x3Fu) return (A & 0xFFFFu) ? 2 : 0;
    return 1;
}

__device__ __forceinline__ int read_mask(const void* meas, size_t idx, int mode) {
    if (mode == 3) return ((const unsigned long long*)meas)[idx] != 0ull;
    if (mode == 1) return ((const uint8_t*)meas)[idx] != 0;
    if (mode == 2) return ((const unsigned short*)meas)[idx] != 0;
    return ((const unsigned*)meas)[idx] != 0u;
}

// Phase 1: one wave per (b,c). Ballot-scan the mask along t; write compacted
// F32 times/values and per-(c,b) counts. Block 0 also stages demo (f32).
__global__ void compact_kernel(const float* __restrict__ demo,
                               const float* __restrict__ times,
                               const float* __restrict__ values,
                               const void* __restrict__ meas,
                               float* __restrict__ ws_time,
                               float* __restrict__ ws_val,
                               int* __restrict__ count,
                               float* __restrict__ ws_demo) {
    __shared__ int s_mode;
    if (threadIdx.x == 0) s_mode = detect_mask_mode(meas);
    __syncthreads();
    const int mode = s_mode;

    if (blockIdx.x == 0 && threadIdx.x < BB * DDIM)
        ws_demo[threadIdx.x] = demo[threadIdx.x];

    int wid = (int)((blockIdx.x * blockDim.x + threadIdx.x) >> 6);
    int lane = (int)(threadIdx.x & 63);
    if (wid >= BB * CC) return;
    int b = wid / CC, c = wid % CC;

    float* wt = ws_time + (size_t)(c * BB + b) * TT;
    float* wv = ws_val + (size_t)(c * BB + b) * TT;

    int kbase = 0;
    for (int t0 = 0; t0 < TT; t0 += 64) {
        int t = t0 + lane;
        size_t idx = (size_t)(b * TT + t) * CC + c;
        int m = read_mask(meas, idx, mode);
        unsigned long long bits = __ballot(m);
        if (m) {
            int pos = kbase + __popcll(bits & ((1ull << lane) - 1ull));
            wt[pos] = times[(size_t)b * TT + t];   // exact f32 copy
            wv[pos] = values[idx];                 // exact f32 copy
        }
        kbase += __popcll(bits);
    }
    if (lane == 0) count[c * BB + b] = kbase;
}

// Phase 2: write the ENTIRE f32 output exactly once, 4 floats (16B) per
// thread, fully coalesced. SLAB_B % 4 == 0 so a group never straddles (ch,b).
template <bool HASWS>
__global__ void fill_kernel(const float* __restrict__ ws_demo,
                            const float* __restrict__ demo_raw,
                            const float* __restrict__ ws_time,
                            const float* __restrict__ ws_val,
                            const int* __restrict__ count,
                            float* __restrict__ out) {
    unsigned g = blockIdx.x * 256u + threadIdx.x;   // vec-group (4 f32 each)
    if (g >= (unsigned)(TOTAL / 4)) return;
    unsigned j = g * 4u;
    unsigned ch = j / (unsigned)SLAB_CH;
    unsigned r = j - ch * (unsigned)SLAB_CH;
    unsigned b = r / (unsigned)SLAB_B;
    unsigned q = r - b * (unsigned)SLAB_B;
    int k = (int)(q / (unsigned)FF);
    int f = (int)(q - (unsigned)k * FF);

    float o[4];
    if (ch < CC) {
        int cnt = HASWS ? count[ch * BB + b] : 0;
        const float* wt = ws_time + (size_t)(ch * BB + b) * TT;
        const float* wv = ws_val + (size_t)(ch * BB + b) * TT;
        int onef = 1 + (int)ch;
#pragma unroll
        for (int s = 0; s < 4; ++s) {
            float v = 0.0f;
            if (k < cnt) {
                if (f == 0) v = wt[k];
                else if (f == onef) v = 1.0f;
                else if (f == 41) v = wv[k];
            }
            o[s] = v;
            if (++f == FF) { f = 0; ++k; }
        }
    } else {
        int d = (int)ch - CC;
        float dv = HASWS ? ws_demo[b * DDIM + d] : demo_raw[(size_t)b * DDIM + d];
#pragma unroll
        for (int s = 0; s < 4; ++s) {
            float v = 0.0f;
            if (k == 0) {
                if (f == 32 + d) v = 1.0f;           // one-hot at depth idx 31+d
                else if (f == 41) v = dv;
            }
            o[s] = v;
            if (++f == FF) { f = 0; ++k; }
        }
    }
    float4 pack = make_float4(o[0], o[1], o[2], o[3]);
    reinterpret_cast<float4*>(out)[g] = pack;
}

// Fallback (ws too small): after fill<false> zeroed everything and wrote
// demo rows, scatter the 3 nonzeros of each masked row directly (f32).
__global__ void scatter_kernel(const float* __restrict__ times,
                               const float* __restrict__ values,
                               const void* __restrict__ meas,
                               float* __restrict__ out) {
    __shared__ int s_mode;
    if (threadIdx.x == 0) s_mode = detect_mask_mode(meas);
    __syncthreads();
    const int mode = s_mode;

    int wid = (int)((blockIdx.x * blockDim.x + threadIdx.x) >> 6);
    int lane = (int)(threadIdx.x & 63);
    if (wid >= BB * CC) return;
    int b = wid / CC, c = wid % CC;

    float* base = out + (size_t)(c * BB + b) * SLAB_B;

    int kbase = 0;
    for (int t0 = 0; t0 < TT; t0 += 64) {
        int t = t0 + lane;
        size_t idx = (size_t)(b * TT + t) * CC + c;
        int m = read_mask(meas, idx, mode);
        unsigned long long bits = __ballot(m);
        if (m) {
            int pos = kbase + __popcll(bits & ((1ull << lane) - 1ull));
            float* row = base + (size_t)pos * FF;
            row[0] = times[(size_t)b * TT + t];
            row[1 + c] = 1.0f;
            row[41] = values[idx];
        }
        kbase += __popcll(bits);
    }
}

extern "C" void kernel_launch(void* const* d_in, const int* in_sizes, int n_in,
                              void* d_out, int out_size, void* d_ws, size_t ws_size,
                              hipStream_t stream) {
    const float* demo   = (const float*)d_in[0];
    const float* times  = (const float*)d_in[1];
    const float* values = (const float*)d_in[2];
    const void*  meas   = d_in[3];
    float* out = (float*)d_out;

    const size_t n_cb = (size_t)CC * BB;                    // 1024
    const size_t ws_need = 2 * n_cb * TT * sizeof(float)    // compacted time/val (16.8MB)
                         + n_cb * sizeof(int)               // counts
                         + (size_t)BB * DDIM * sizeof(float); // staged demo
    const long ngroups = TOTAL / 4;                         // 27,525,120
    const int fill_blocks = (int)((ngroups + 255) / 256);   // 107,520
    const int scan_blocks = (BB * CC * 64 + 255) / 256;     // 256

    if (ws_size >= ws_need) {
        float* ws_time = (float*)d_ws;
        float* ws_val  = ws_time + n_cb * TT;
        int* count     = (int*)(ws_val + n_cb * TT);
        float* ws_demo = (float*)(count + n_cb);
        compact_kernel<<<scan_blocks, 256, 0, stream>>>(demo, times, values, meas,
                                                        ws_time, ws_val, count, ws_demo);
        fill_kernel<true><<<fill_blocks, 256, 0, stream>>>(ws_demo, nullptr,
                                                           ws_time, ws_val, count, out);
    } else {
        fill_kernel<false><<<fill_blocks, 256, 0, stream>>>(nullptr, demo,
                                                            nullptr, nullptr, nullptr, out);
        scatter_kernel<<<scan_blocks, 256, 0, stream>>>(times, values, meas, out);
    }
}

// Round 16
// 470.423 us; speedup vs baseline: 1.0287x; 1.0287x over previous
//
#include <hip/hip_runtime.h>
#include <stdint.h>

// Problem constants (B,T,C,DD) = (32, 2048, 32, 8)
#define BB 32
#define TT 2048
#define CC 32
#define DDIM 8
#define FF 42                  // DEPTH + 2 = (8+32) + 2
#define SLAB_B (TT * FF)       // 86016 elems per (ch,b)
#define SLAB_CH (BB * SLAB_B)  // 2752512 elems per ch
#define TOTAL (40L * SLAB_CH)  // 110100480 f32 elems

// Mask modes: 0=word(int32/f32 0-1) 1=byte 2=short 3=qword(int64)
__device__ __forceinline__ int read_mask(const void* meas, size_t idx, int mode) {
    if (mode == 3) return ((const unsigned long long*)meas)[idx] != 0ull;
    if (mode == 1) return ((const uint8_t*)meas)[idx] != 0;
    if (mode == 2) return ((const unsigned short*)meas)[idx] != 0;
    return ((const unsigned*)meas)[idx] != 0u;
}

// Parallel mask-layout detection (256 threads + LDS atomicOr) — replaces the
// 256 serial loads by thread 0 (a ~20µs block-serialized chain in round 15).
__device__ __forceinline__ int block_detect_mask_mode(const void* meas,
                                                      unsigned* s_A, unsigned* s_Aodd) {
    if (threadIdx.x == 0) { *s_A = 0u; *s_Aodd = 0u; }
    __syncthreads();
    if (threadIdx.x < 256) {
        unsigned w = ((const unsigned*)meas)[threadIdx.x];
        atomicOr(s_A, w);
        if (threadIdx.x & 1) atomicOr(s_Aodd, w);
    }
    __syncthreads();
    unsigned A = *s_A, Aodd = *s_Aodd;
    unsigned hi = A >> 24;
    if (hi == 0u) return (Aodd == 0u) ? 3 : 0;            // int64 : int32
    if (hi >= 0x3Cu && hi <= 0x3Fu) return (A & 0xFFFFu) ? 2 : 0;
    return 1;
}

// Phase 1: one 512-thread block per (c,b). 8 waves split T=2048 into 256-long
// chunks; two-phase ballot scan (popcount -> LDS prefix -> write). Serial
// chain is 4 iterations (was 32), occupancy 8192 waves (was 1024).
__global__ __launch_bounds__(512)
void compact_kernel(const float* __restrict__ demo,
                    const float* __restrict__ times,
                    const float* __restrict__ values,
                    const void* __restrict__ meas,
                    float* __restrict__ ws_time,
                    float* __restrict__ ws_val,
                    int* __restrict__ count,
                    float* __restrict__ ws_demo) {
    __shared__ unsigned s_A, s_Aodd;
    __shared__ int s_wcnt[8];
    const int mode = block_detect_mask_mode(meas, &s_A, &s_Aodd);

    const int bid = blockIdx.x;            // = c*BB + b
    const int c = bid >> 5, b = bid & 31;  // BB = 32
    const int w = threadIdx.x >> 6;        // wave 0..7
    const int lane = threadIdx.x & 63;
    const int tbase = w * 256;

    if (bid == 0 && threadIdx.x < BB * DDIM)
        ws_demo[threadIdx.x] = demo[threadIdx.x];

    // phase A: per-wave popcount
    int mycnt = 0;
#pragma unroll
    for (int i = 0; i < 4; ++i) {
        int t = tbase + i * 64 + lane;
        size_t idx = (size_t)(b * TT + t) * CC + c;
        mycnt += __popcll(__ballot(read_mask(meas, idx, mode)));
    }
    if (lane == 0) s_wcnt[w] = mycnt;
    __syncthreads();

    int base = 0;
#pragma unroll
    for (int i = 0; i < 8; ++i) if (i < w) base += s_wcnt[i];
    if (threadIdx.x == 0) {
        int tot = 0;
#pragma unroll
        for (int i = 0; i < 8; ++i) tot += s_wcnt[i];
        count[bid] = tot;
    }

    float* wt = ws_time + (size_t)bid * TT;
    float* wv = ws_val + (size_t)bid * TT;

    // phase B: re-scan (mask now L1-hot) and write compacted values
    int kbase = base;
#pragma unroll
    for (int i = 0; i < 4; ++i) {
        int t = tbase + i * 64 + lane;
        size_t idx = (size_t)(b * TT + t) * CC + c;
        int m = read_mask(meas, idx, mode);
        unsigned long long bits = __ballot(m);
        if (m) {
            int pos = kbase + __popcll(bits & ((1ull << lane) - 1ull));
            wt[pos] = times[(size_t)b * TT + t];   // exact f32 copy
            wv[pos] = values[idx];                 // exact f32 copy
        }
        kbase += __popcll(bits);
    }
}

// Phase 2: write the ENTIRE f32 output exactly once, 8 floats (2x float4,
// 32B) per thread, fully coalesced. SLAB_B % 8 == 0 -> no (ch,b) straddle.
template <bool HASWS>
__global__ __launch_bounds__(256)
void fill_kernel(const float* __restrict__ ws_demo,
                 const float* __restrict__ demo_raw,
                 const float* __restrict__ ws_time,
                 const float* __restrict__ ws_val,
                 const int* __restrict__ count,
                 float* __restrict__ out) {
    unsigned g = blockIdx.x * 256u + threadIdx.x;   // 8 elems each
    if (g >= (unsigned)(TOTAL / 8)) return;
    unsigned j = g * 8u;
    unsigned ch = j / (unsigned)SLAB_CH;
    unsigned r = j - ch * (unsigned)SLAB_CH;
    unsigned b = r / (unsigned)SLAB_B;
    unsigned q = r - b * (unsigned)SLAB_B;
    int k = (int)(q / (unsigned)FF);
    int f = (int)(q - (unsigned)k * FF);

    float o[8];
    if (ch < CC) {
        int cnt = HASWS ? count[ch * BB + b] : 0;
        const float* wt = ws_time + (size_t)(ch * BB + b) * TT;
        const float* wv = ws_val + (size_t)(ch * BB + b) * TT;
        int onef = 1 + (int)ch;
#pragma unroll
        for (int s = 0; s < 8; ++s) {
            float v = 0.0f;
            if (k < cnt) {
                if (f == 0) v = wt[k];
                else if (f == onef) v = 1.0f;
                else if (f == 41) v = wv[k];
            }
            o[s] = v;
            if (++f == FF) { f = 0; ++k; }
        }
    } else {
        int d = (int)ch - CC;
        float dv = HASWS ? ws_demo[b * DDIM + d] : demo_raw[(size_t)b * DDIM + d];
#pragma unroll
        for (int s = 0; s < 8; ++s) {
            float v = 0.0f;
            if (k == 0) {
                if (f == 32 + d) v = 1.0f;           // one-hot at depth idx 31+d
                else if (f == 41) v = dv;
            }
            o[s] = v;
            if (++f == FF) { f = 0; ++k; }
        }
    }
    float4* dst = reinterpret_cast<float4*>(out) + (size_t)g * 2;
    dst[0] = make_float4(o[0], o[1], o[2], o[3]);
    dst[1] = make_float4(o[4], o[5], o[6], o[7]);
}

// Fallback (ws too small): after fill<false> zeroed everything and wrote
// demo rows, scatter the 3 nonzeros of each masked row directly (f32).
__global__ void scatter_kernel(const float* __restrict__ times,
                               const float* __restrict__ values,
                               const void* __restrict__ meas,
                               float* __restrict__ out) {
    __shared__ unsigned s_A, s_Aodd;
    const int mode = block_detect_mask_mode(meas, &s_A, &s_Aodd);

    int wid = (int)((blockIdx.x * blockDim.x + threadIdx.x) >> 6);
    int lane = (int)(threadIdx.x & 63);
    if (wid >= BB * CC) return;
    int b = wid / CC, c = wid % CC;

    float* base = out + (size_t)(c * BB + b) * SLAB_B;

    int kbase = 0;
    for (int t0 = 0; t0 < TT; t0 += 64) {
        int t = t0 + lane;
        size_t idx = (size_t)(b * TT + t) * CC + c;
        int m = read_mask(meas, idx, mode);
        unsigned long long bits = __ballot(m);
        if (m) {
            int pos = kbase + __popcll(bits & ((1ull << lane) - 1ull));
            float* row = base + (size_t)pos * FF;
            row[0] = times[(size_t)b * TT + t];
            row[1 + c] = 1.0f;
            row[41] = values[idx];
        }
        kbase += __popcll(bits);
    }
}

extern "C" void kernel_launch(void* const* d_in, const int* in_sizes, int n_in,
                              void* d_out, int out_size, void* d_ws, size_t ws_size,
                              hipStream_t stream) {
    const float* demo   = (const float*)d_in[0];
    const float* times  = (const float*)d_in[1];
    const float* values = (const float*)d_in[2];
    const void*  meas   = d_in[3];
    float* out = (float*)d_out;

    const size_t n_cb = (size_t)CC * BB;                    // 1024
    const size_t ws_need = 2 * n_cb * TT * sizeof(float)    // compacted time/val (16.8MB)
                         + n_cb * sizeof(int)               // counts
                         + (size_t)BB * DDIM * sizeof(float); // staged demo
    const int fill_blocks = (int)(TOTAL / 8 / 256);         // 53,760 exact
    const int scan_blocks = (BB * CC * 64 + 255) / 256;     // 256 (fallback)

    if (ws_size >= ws_need) {
        float* ws_time = (float*)d_ws;
        float* ws_val  = ws_time + n_cb * TT;
        int* count     = (int*)(ws_val + n_cb * TT);
        float* ws_demo = (float*)(count + n_cb);
        compact_kernel<<<BB * CC, 512, 0, stream>>>(demo, times, values, meas,
                                                    ws_time, ws_val, count, ws_demo);
        fill_kernel<true><<<fill_blocks, 256, 0, stream>>>(ws_demo, nullptr,
                                                           ws_time, ws_val, count, out);
    } else {
        fill_kernel<false><<<fill_blocks, 256, 0, stream>>>(nullptr, demo,
                                                            nullptr, nullptr, nullptr, out);
        scatter_kernel<<<scan_blocks, 256, 0, stream>>>(times, values, meas, out);
    }
}